// Round 1
// baseline (580.680 us; speedup 1.0000x reference)
//
#include <hip/hip_runtime.h>
#include <hip/hip_bf16.h>

// Problem constants (shapes fixed by the reference)
#define T_TOK 4096        // tokens
#define I1    512         // layer1 in
#define O1    2049        // layer1 out
#define O1P   2176        // layer1 out padded to 17*128
#define K1    4608        // 8*512 (spline block) + 512 (silu block)
#define I2    2049        // layer2 in
#define O2    512         // layer2 out
#define SP2   16392       // 8*2049 spline block size
#define K2V   18441       // valid K2 = 16392 + 2049
#define K2    18560       // padded to 290*64
#define SPLITS2 5
#define KLEN2  3712       // K2 / SPLITS2

typedef __attribute__((ext_vector_type(8))) short short8;
typedef __attribute__((ext_vector_type(4))) float floatx4;
typedef __attribute__((address_space(3))) void* lds_ptr_t;
typedef const __attribute__((address_space(1))) void* gmem_ptr_t;

__device__ __forceinline__ unsigned short f2bf(float f) {
  union { __hip_bfloat16 h; unsigned short u; } cv;
  cv.h = __float2bfloat16(f);
  return cv.u;
}

__device__ __forceinline__ float silu_f(float x) {
  return x / (1.0f + __expf(-x));
}

// Cubic B-spline bases on uniform grid [-2.2, 2.2], h=0.4 (12 knots -> 8 deg-3 bases).
// For x in knot interval j (0..10), nonzero bases are columns j-3..j with the
// classic uniform cubic blending functions of t=(x-g_j)/h. Outside [-2.2,2.2): all 0
// (matches reference's (x>=g_i)&(x<g_{i+1}) degree-0 seed).
__device__ __forceinline__ void bspline8(float x, unsigned short o[8]) {
#pragma unroll
  for (int c = 0; c < 8; ++c) o[c] = 0;
  if (x >= -2.2f && x < 2.2f) {
    float u = (x + 2.2f) * 2.5f;
    int j = (int)u;
    if (j > 10) j = 10;
    float t = u - (float)j;
    float it = 1.0f - t;
    float t2 = t * t, t3 = t2 * t;
    float b0 = it * it * it * (1.0f / 6.0f);
    float b1 = (3.0f * t3 - 6.0f * t2 + 4.0f) * (1.0f / 6.0f);
    float b2 = (-3.0f * t3 + 3.0f * t2 + 3.0f * t + 1.0f) * (1.0f / 6.0f);
    float b3 = t3 * (1.0f / 6.0f);
    int c0 = j - 3;
#pragma unroll
    for (int d = 0; d < 4; ++d) {
      int c = c0 + d;
      float bv = (d == 0) ? b0 : (d == 1) ? b1 : (d == 2) ? b2 : b3;
      if (c >= 0 && c < 8) o[c] = f2bf(bv);
    }
  }
}

// A1[n, k]: k<4096 -> basis_{k&7}(x[n, k>>3]); k>=4096 -> silu(x[n, k-4096])
__global__ void expand1_kernel(const float* __restrict__ X, unsigned short* __restrict__ A1) {
  int g = blockIdx.x * 256 + threadIdx.x;   // 0 .. 4096*512-1
  int n = g >> 9;
  int i = g & 511;
  float x = X[g];
  A1[(size_t)n * K1 + 4096 + i] = f2bf(silu_f(x));
  union { unsigned short s[8]; uint4 v; } pk;
  bspline8(x, pk.s);
  *(uint4*)&A1[(size_t)n * K1 + (size_t)i * 8] = pk.v;  // byte off = n*9216+16i, 16B aligned
}

// A2 row layout: [spline 16392 | silu 2049 | zero pad 119]
__global__ void expand2_kernel(const float* __restrict__ H, unsigned short* __restrict__ A2) {
  int i = blockIdx.x * 256 + threadIdx.x;
  int n = blockIdx.y;
  if (i >= 2176) return;
  unsigned short* row = A2 + (size_t)n * K2;
  if (i < I2) {
    float h = H[(size_t)n * I2 + i];
    row[SP2 + i] = f2bf(silu_f(h));
    union { unsigned short s[8]; uint4 v; } pk;
    bspline8(h, pk.s);
    *(uint4*)&row[(size_t)i * 8] = pk.v;   // byte off = n*37120+16i, 16B aligned
  } else if (i < 2176 - 8) {               // i in [2049,2168): zero pad cols [18441,18560)
    row[SP2 + i] = 0;
  }
}

// W1'[o, k]: k<4096 -> spline_w1[o,k>>3,k&7]*scaler1[o,k>>3]; else base_w1[o,k-4096]; o>=2049 -> 0
__global__ void pack_w1_kernel(const float* __restrict__ bw, const float* __restrict__ sw,
                               const float* __restrict__ sc, unsigned short* __restrict__ W) {
  int k = blockIdx.x * 256 + threadIdx.x;  // < 4608 (grid exact)
  int o = blockIdx.y;                      // < 2176
  float v = 0.0f;
  if (o < O1) {
    if (k < 4096) v = sw[(size_t)o * 4096 + k] * sc[(size_t)o * I1 + (k >> 3)];
    else          v = bw[(size_t)o * I1 + (k - 4096)];
  }
  W[(size_t)o * K1 + k] = f2bf(v);
}

// W2'[o, k]: k<16392 -> spline_w2[o,k>>3,k&7]*scaler2[o,k>>3]; k<18441 -> base_w2[o,k-16392]; else 0
__global__ void pack_w2_kernel(const float* __restrict__ bw, const float* __restrict__ sw,
                               const float* __restrict__ sc, unsigned short* __restrict__ W) {
  int k = blockIdx.x * 256 + threadIdx.x;
  if (k >= K2) return;
  int o = blockIdx.y;                      // < 512
  float v = 0.0f;
  if (k < SP2)       v = sw[(size_t)o * SP2 + k] * sc[(size_t)o * I2 + (k >> 3)];
  else if (k < K2V)  v = bw[(size_t)o * I2 + (k - SP2)];
  W[(size_t)o * K2 + k] = f2bf(v);
}

// C(MxN fp32) = A(M x K bf16, row-major) @ B(N x K bf16, row-major)^T
// 128x128 tile, BK=64, 4 waves (2x2), 16x16x32 bf16 MFMA, global_load_lds staging
// with XOR chunk swizzle (LDS[r][cl] = G[r][cl ^ (r&7)]) for conflict-free b128 frag reads.
// blockIdx.z = split-K index; useAtomic accumulates via fp32 atomicAdd (C pre-zeroed).
__global__ __launch_bounds__(256)
void gemm_bt_kernel(const unsigned short* __restrict__ A,
                    const unsigned short* __restrict__ B,
                    float* __restrict__ C,
                    int N, int lda, int ldc, int kLen, int useAtomic)
{
  __shared__ __align__(16) unsigned short As[128 * 64];
  __shared__ __align__(16) unsigned short Bs[128 * 64];

  const int tid = threadIdx.x;
  const int bx = blockIdx.x, by = blockIdx.y;
  const int ks = blockIdx.z * kLen;
  const int ke = ks + kLen;

  const int w = tid >> 6, L = tid & 63, q = L >> 4, ln = L & 15;
  const int wm = (w & 1) << 6, wn = (w >> 1) << 6;

  floatx4 zero = {0.f, 0.f, 0.f, 0.f};
  floatx4 acc[4][4];
#pragma unroll
  for (int mt = 0; mt < 4; ++mt)
#pragma unroll
    for (int nt = 0; nt < 4; ++nt)
      acc[mt][nt] = zero;

  const long aRow0 = (long)by * 128;
  const long bRow0 = (long)bx * 128;

  for (int kc = ks; kc < ke; kc += 64) {
    __syncthreads();   // protect LDS from prior iteration's readers
#pragma unroll
    for (int r = 0; r < 4; ++r) {
      int e = r * 256 + tid;           // chunk id; lds dest = e*16B (lane-contiguous per wave)
      int row = e >> 3;
      int cg = (e & 7) ^ (row & 7);    // swizzled global chunk
      const unsigned short* ga = A + (aRow0 + row) * (long)lda + kc + cg * 8;
      __builtin_amdgcn_global_load_lds((gmem_ptr_t)ga, (lds_ptr_t)&As[e * 8], 16, 0, 0);
      const unsigned short* gb = B + (bRow0 + row) * (long)lda + kc + cg * 8;
      __builtin_amdgcn_global_load_lds((gmem_ptr_t)gb, (lds_ptr_t)&Bs[e * 8], 16, 0, 0);
    }
    __syncthreads();   // staging complete (compiler emits vmcnt drain)
#pragma unroll
    for (int s = 0; s < 2; ++s) {
      short8 af[4], bf[4];
#pragma unroll
      for (int mt = 0; mt < 4; ++mt) {
        int row = wm + mt * 16 + ln;
        int cl = ((s << 2) + q) ^ (row & 7);
        af[mt] = *(const short8*)&As[row * 64 + cl * 8];
      }
#pragma unroll
      for (int nt = 0; nt < 4; ++nt) {
        int row = wn + nt * 16 + ln;
        int cl = ((s << 2) + q) ^ (row & 7);
        bf[nt] = *(const short8*)&Bs[row * 64 + cl * 8];
      }
#pragma unroll
      for (int mt = 0; mt < 4; ++mt)
#pragma unroll
        for (int nt = 0; nt < 4; ++nt)
          acc[mt][nt] = __builtin_amdgcn_mfma_f32_16x16x32_bf16(af[mt], bf[nt], acc[mt][nt], 0, 0, 0);
    }
  }

  // Epilogue: D col = lane&15 (n), row = q*4+reg (m)  [m89-verified layout]
#pragma unroll
  for (int mt = 0; mt < 4; ++mt) {
#pragma unroll
    for (int nt = 0; nt < 4; ++nt) {
      int n = bx * 128 + wn + nt * 16 + ln;
      if (n < N) {
        int m0 = by * 128 + wm + mt * 16 + q * 4;
#pragma unroll
        for (int rg = 0; rg < 4; ++rg) {
          long off = (long)(m0 + rg) * ldc + n;
          float v = acc[mt][nt][rg];
          if (useAtomic) atomicAdd(&C[off], v);
          else           C[off] = v;
        }
      }
    }
  }
}

extern "C" void kernel_launch(void* const* d_in, const int* in_sizes, int n_in,
                              void* d_out, int out_size, void* d_ws, size_t ws_size,
                              hipStream_t stream) {
  const float* x   = (const float*)d_in[0];
  const float* bw1 = (const float*)d_in[1];
  const float* sw1 = (const float*)d_in[2];
  const float* sc1 = (const float*)d_in[3];
  const float* bw2 = (const float*)d_in[4];
  const float* sw2 = (const float*)d_in[5];
  const float* sc2 = (const float*)d_in[6];
  float* out = (float*)d_out;

  // Workspace layout: A1 | W1' | W2' | H | A2(chunk)
  char* ws = (char*)d_ws;
  unsigned short* A1 = (unsigned short*)ws;                     // 4096*4608*2  = 37,748,736 B
  unsigned short* W1 = A1 + (size_t)T_TOK * K1;                 // 2176*4608*2  = 20,054,016 B
  unsigned short* W2 = W1 + (size_t)O1P * K1;                   //  512*18560*2 = 19,005,440 B
  float*          H  = (float*)(W2 + (size_t)O2 * K2);          // 4096*2049*4  = 33,570,816 B
  unsigned short* A2 = (unsigned short*)(H + (size_t)T_TOK * I2);
  size_t fixedBytes = (size_t)((char*)A2 - ws);                 // ~110.4 MB, 16B-aligned
  size_t rem = ws_size > fixedBytes ? ws_size - fixedBytes : 0;
  long rpcL = (long)(rem / ((size_t)K2 * 2));                   // rows of A2 that fit
  int rpc = (int)((rpcL / 128) * 128);
  if (rpc > T_TOK) rpc = T_TOK;
  if (rpc < 128)   rpc = 128;  // below this ws_size is insufficient anyway

  hipMemsetAsync(d_out, 0, (size_t)out_size * sizeof(float), stream);

  pack_w1_kernel<<<dim3(K1 / 256, O1P), 256, 0, stream>>>(bw1, sw1, sc1, W1);
  pack_w2_kernel<<<dim3((K2 + 255) / 256, O2), 256, 0, stream>>>(bw2, sw2, sc2, W2);
  expand1_kernel<<<(T_TOK * I1) / 256, 256, 0, stream>>>(x, A1);

  // Layer 1: H = A1 @ W1'^T   (M=4096, N=2049(pad 2176), K=4608), 544 blocks
  gemm_bt_kernel<<<dim3(O1P / 128, T_TOK / 128, 1), 256, 0, stream>>>(
      A1, W1, H, O1, K1, O1, K1, 0);

  // Layer 2: out += A2 @ W2'^T  (M=chunk, N=512, K=18560, split-K=5), atomic accumulate
  for (int m0 = 0; m0 < T_TOK; m0 += rpc) {
    int rows = (T_TOK - m0 < rpc) ? (T_TOK - m0) : rpc;
    expand2_kernel<<<dim3(9, rows), 256, 0, stream>>>(H + (size_t)m0 * I2, A2);
    gemm_bt_kernel<<<dim3(O2 / 128, rows / 128, SPLITS2), 256, 0, stream>>>(
        A2, W2, out + (size_t)m0 * O2, O2, K2, O2, KLEN2, 1);
  }
}